// Round 1
// baseline (205.111 us; speedup 1.0000x reference)
//
#include <hip/hip_runtime.h>
#include <math.h>

typedef unsigned short u16;
typedef unsigned int   u32;
typedef __attribute__((ext_vector_type(8))) short short8;
typedef __attribute__((ext_vector_type(4))) float f32x4;

// ws layout (float offsets). ws_size = 256 MiB.
#define OFS_XB   0ul          // 32768 x 512 bf16: [pixel][ch]; ch 0-255 = x, 256-511 = agg
#define OFS_W1B  8388608ul    // 256x256 bf16 folded embed weights [o][k]
#define OFS_W2B  8421376ul    // 256x512 bf16 folded enhance weights [o][k]
#define OFS_B1   8486912ul    // 256 fp32
#define OFS_B2   8487168ul    // 256 fp32
#define OFS_POOL 8487424ul    // 8*512 fp32 (atomic-accumulated means)
#define OFS_ENH  8491520ul    // 32768x256 bf16 enhanced

__device__ __forceinline__ u16 f2bf(float x) {
    union { float f; u32 u; } v; v.f = x;
    u32 r = v.u + 0x7fffu + ((v.u >> 16) & 1u);
    return (u16)(r >> 16);
}
__device__ __forceinline__ float bf2f(u16 h) {
    union { u32 u; float f; } v; v.u = ((u32)h) << 16;
    return v.f;
}
__device__ __forceinline__ void ld_g2l_16(u16* l, const u16* g) {
    __builtin_amdgcn_global_load_lds(
        (const __attribute__((address_space(1))) u32*)g,
        (__attribute__((address_space(3))) u32*)l,
        16, 0, 0);
}

// ---------------- cvt (+fused prep): pool zero FIRST, then weights, then x->xb ----------------
// id 0: pool zero. 1-770: weight fold. 771-2818: cvt + x-pool.
__global__ __launch_bounds__(256) void k_cvt(
    const float* __restrict__ x, u16* __restrict__ xb, float* __restrict__ pool,
    const float* __restrict__ w1, const float* __restrict__ b1,
    const float* __restrict__ g1, const float* __restrict__ be1,
    const float* __restrict__ m1, const float* __restrict__ v1,
    const float* __restrict__ w2, const float* __restrict__ b2,
    const float* __restrict__ g2, const float* __restrict__ be2,
    const float* __restrict__ m2, const float* __restrict__ v2,
    u16* __restrict__ w1b, u16* __restrict__ w2b,
    float* __restrict__ b1f, float* __restrict__ b2f)
{
    __shared__ float tile[64][65];
    const int t = threadIdx.x;
    const int id = blockIdx.x;
    if (id < 1) {                            // pool zero (16 KiB), dispatched before any atomics
        const float4 z = {0.f, 0.f, 0.f, 0.f};
#pragma unroll
        for (int i = 0; i < 4; ++i) ((float4*)pool)[i * 256 + t] = z;
        return;
    }
    if (id < 771) {                          // weight prep
        int idx = (id - 1) * 256 + t;
        if (idx < 65536) {
            int o = idx >> 8;
            float inv = g1[o] * rsqrtf(v1[o] + 1e-5f);
            w1b[idx] = f2bf(w1[idx] * inv);
        } else if (idx < 196608) {
            int j = idx - 65536;
            int o = j >> 9;
            float inv = g2[o] * rsqrtf(v2[o] + 1e-5f);
            w2b[j] = f2bf(w2[j] * inv);
        } else if (idx < 196864) {
            int o = idx - 196608;
            float inv = g1[o] * rsqrtf(v1[o] + 1e-5f);
            b1f[o] = b1[o] * inv + be1[o] - m1[o] * inv;
        } else if (idx < 197120) {
            int o = idx - 196864;
            float inv = g2[o] * rsqrtf(v2[o] + 1e-5f);
            b2f[o] = b2[o] * inv + be2[o] - m2[o] * inv;
        }
        return;
    }
    const int cid = id - 771;                // 0..2047
    const int pt = cid & 63, ct = (cid >> 6) & 3, b = cid >> 8;
    const float* src = x + (((size_t)(b * 256 + ct * 64)) << 12) + pt * 64;
#pragma unroll
    for (int i = 0; i < 16; ++i) {
        int idx = i * 256 + t;
        int cl = idx >> 6, pl = idx & 63;
        tile[cl][pl] = src[((size_t)cl << 12) + pl];
    }
    __syncthreads();
#pragma unroll
    for (int i = 0; i < 8; ++i) {
        int idx = i * 256 + t;
        int pl = idx >> 5, c2 = idx & 31;
        int cl = c2 * 2;
        u32 lo = f2bf(tile[cl][pl]);
        u32 hi = f2bf(tile[cl + 1][pl]);
        *(u32*)(xb + (((size_t)(b * 4096 + pt * 64 + pl)) << 9) + ct * 64 + cl) = lo | (hi << 16);
    }
    if (t < 64) {
        float s = 0.f;
#pragma unroll
        for (int i = 0; i < 64; ++i) s += tile[t][i];
        atomicAdd(&pool[(b << 9) + ct * 64 + t], s * (1.f / 4096.f));
    }
}

// ---------------- bf16 MFMA GEMM: out = relu(W @ X + bias) [+ fused pool] ----------------
// 1-D grid 512. o=(id>>3)&1, p_tile=((id>>4)<<3)|(id&7): both o-blocks of a
// p-tile land on XCD p_tile%8, 8 dispatch-ids apart -> X tile L2-shared.
template<int KIN, bool OUTBF, bool DOPOOL>
__global__ __launch_bounds__(256) void k_gemm(
    const u16* __restrict__ xb, const u16* __restrict__ Wb,
    const float* __restrict__ biasf, void* __restrict__ outp,
    float* __restrict__ poolp)
{
    __shared__ __align__(16) u16 Wl[4096];
    __shared__ __align__(16) u16 Xl[4096];
    __shared__ float sbias[128];
    const int t = threadIdx.x;
    const int lane = t & 63;
    const int wv = t >> 6;
    const int id = blockIdx.x;
    const int p_blk = (((id >> 4) << 3) | (id & 7)) * 128;
    const int o_blk = ((id >> 3) & 1) * 128;
    const int owg = (wv & 1) * 4;
    const int pwg = (wv >> 1) * 4;
    const int r16 = lane & 15, q = lane >> 4;
    if (t < 128) sbias[t] = biasf[o_blk + t];

    f32x4 acc[4][4];
#pragma unroll
    for (int i = 0; i < 4; ++i)
#pragma unroll
        for (int j = 0; j < 4; ++j) acc[i][j] = (f32x4){0.f, 0.f, 0.f, 0.f};

    for (int kc = 0; kc < KIN / 32; ++kc) {
        const int kk = kc * 32 + q * 8;
#pragma unroll
        for (int s = 0; s < 4; ++s) {
            const int bi = wv * 4 + s;
            const u16* g;
            u16* l;
            if (bi < 8) {
                g = Wb + (size_t)(o_blk + bi * 16 + r16) * KIN + kk;
                l = Wl + bi * 512;
            } else {
                g = xb + (((size_t)(p_blk + (bi - 8) * 16 + r16)) << 9) + kk;
                l = Xl + (bi - 8) * 512;
            }
            ld_g2l_16(l, g);
        }
        __syncthreads();
        short8 af[4], bf[4];
#pragma unroll
        for (int i = 0; i < 4; ++i) af[i] = *(const short8*)(Wl + (owg + i) * 512 + lane * 8);
#pragma unroll
        for (int j = 0; j < 4; ++j) bf[j] = *(const short8*)(Xl + (pwg + j) * 512 + lane * 8);
#pragma unroll
        for (int i = 0; i < 4; ++i)
#pragma unroll
            for (int j = 0; j < 4; ++j)
                acc[i][j] = __builtin_amdgcn_mfma_f32_16x16x32_bf16(af[i], bf[j], acc[i][j], 0, 0, 0);
        __syncthreads();
    }

    float bia[4][4];
#pragma unroll
    for (int i = 0; i < 4; ++i)
#pragma unroll
        for (int r = 0; r < 4; ++r) bia[i][r] = sbias[owg * 16 + i * 16 + q * 4 + r];
    const int bidx = p_blk >> 12;
    const int pin0 = (p_blk & 4095) + pwg * 16 + r16;
#pragma unroll
    for (int i = 0; i < 4; ++i) {
#pragma unroll
        for (int r = 0; r < 4; ++r) {
            const int o = o_blk + owg * 16 + i * 16 + q * 4 + r;
            const size_t rowb = ((size_t)(bidx * 256 + o)) << 12;
            float ps = 0.f;
#pragma unroll
            for (int j = 0; j < 4; ++j) {
                float v = fmaxf(acc[i][j][r] + bia[i][r], 0.f);
                const size_t oi = rowb + pin0 + j * 16;
                ((u16*)outp)[oi] = f2bf(v);
                ps += v;
            }
            if (DOPOOL) {
                ps += __shfl_down(ps, 8, 16);
                ps += __shfl_down(ps, 4, 16);
                ps += __shfl_down(ps, 2, 16);
                ps += __shfl_down(ps, 1, 16);
                if (r16 == 0)
                    atomicAdd(&poolp[(bidx << 9) + 256 + o], ps * (1.f / 4096.f));
            }
        }
    }
}

// ---------------- fused sim + softmax + aggregation ----------------
// Block = (b, h): stages ALL 256 ch of 3 fe rows (96 KB LDS), computes the 9
// window dots AND the 3 row-norm planes locally (no pd round-trip, no atomics),
// wave-0 softmax runs while the x rows are async-staged into the SAME buffer,
// then aggregation writes the agg half of xb. XCD map: b = id&7.
__global__ __launch_bounds__(512) void k_simagg(
    const u16* __restrict__ fe, const u16* __restrict__ xb, u16* __restrict__ xbo)
{
    __shared__ __align__(16) u16 st[3 * 16384];   // 96 KiB; phase A: fe [r][c][px], phase B: x [r][px][c]
    __shared__ float red[8][64][13];              // 8 slices x 64 px x (9 dots + 3 norms), padded
    __shared__ float ws9[9][64];
    const int t = threadIdx.x;
    const int id = blockIdx.x;
    const int b = id & 7, h = id >> 3;
    const int rows[3] = {h > 0 ? h - 1 : 0, h, h < 63 ? h + 1 : 63};

    // ---- phase A stage: fe rows, layout [r][ch][px]
    {
        const u16* base = fe + ((size_t)(b * 256) << 12);
#pragma unroll
        for (int it = 0; it < 12; ++it) {
            const int flat = it * 512 + t;
            const int r = flat >> 11, j = flat & 2047;     // j = c*8 + chunk
            const u16* gs = base + ((size_t)(j >> 3) << 12) + rows[r] * 64 + (j & 7) * 8;
            ld_g2l_16(st + r * 16384 + j * 8, gs);
        }
    }
    __syncthreads();
    const int w = t & 63, sl = t >> 6;
    {
        const int wl = w > 0 ? w - 1 : 0, wr = w < 63 ? w + 1 : 63;
        float dot[9] = {};
        float nn[3] = {};
        const u16* s0 = st + sl * 2048;                    // 32-ch slice
#pragma unroll 4
        for (int ci = 0; ci < 32; ++ci) {
            const u16* pc = s0 + ci * 64;
            float v[9];
#pragma unroll
            for (int r = 0; r < 3; ++r) {
                v[r * 3 + 0] = bf2f(pc[r * 16384 + wl]);
                v[r * 3 + 1] = bf2f(pc[r * 16384 + w]);
                v[r * 3 + 2] = bf2f(pc[r * 16384 + wr]);
            }
            const float c0 = v[4];
#pragma unroll
            for (int k = 0; k < 9; ++k) dot[k] = fmaf(c0, v[k], dot[k]);
#pragma unroll
            for (int r = 0; r < 3; ++r) nn[r] = fmaf(v[r * 3 + 1], v[r * 3 + 1], nn[r]);
        }
#pragma unroll
        for (int k = 0; k < 9; ++k) red[sl][w][k] = dot[k];
#pragma unroll
        for (int r = 0; r < 3; ++r) red[sl][w][9 + r] = nn[r];
    }
    __syncthreads();                                       // all st reads done
    // ---- phase B stage issue (overwrites st with x rows, layout [r][px][ch])
    {
        const u16* base = xb + ((size_t)(b * 4096) << 9);
#pragma unroll
        for (int it = 0; it < 12; ++it) {
            const int flat = it * 512 + t;
            const int r = flat >> 11, j = flat & 2047;     // j = px*32 + cc
            const u16* gs = base + (((size_t)(rows[r] * 64 + (j >> 5))) << 9) + (j & 31) * 8;
            ld_g2l_16(st + r * 16384 + j * 8, gs);
        }
    }
    // ---- softmax finalize on wave 0 while stage-B is in flight
    if (t < 64) {
        float dk[9], nr[3];
#pragma unroll
        for (int k = 0; k < 9; ++k) {
            float s = red[0][w][k];
#pragma unroll
            for (int g = 1; g < 8; ++g) s += red[g][w][k];
            dk[k] = s;
        }
#pragma unroll
        for (int r = 0; r < 3; ++r) {
            float s = red[0][w][9 + r];
#pragma unroll
            for (int g = 1; g < 8; ++g) s += red[g][w][9 + r];
            nr[r] = s;
        }
        const float nc = sqrtf(nr[1]);
        float sv[9], mk[9];
#pragma unroll
        for (int di = -1; di <= 1; ++di) {
#pragma unroll
            for (int dj = -1; dj <= 1; ++dj) {
                const int k = (di + 1) * 3 + (dj + 1);
                const int hn = h + di, wn = w + dj;
                const float mask = (hn >= 0 && hn < 64 && wn >= 0 && wn < 64) ? 1.f : 0.f;
                const int wc = wn < 0 ? 0 : (wn > 63 ? 63 : wn);
                const float nk = __shfl(nr[di + 1], wc, 64);
                mk[k] = mask;
                sv[k] = mask * dk[k] / (nc * sqrtf(nk) + 1e-7f);
            }
        }
        float mx = sv[0];
#pragma unroll
        for (int k = 1; k < 9; ++k) mx = fmaxf(mx, sv[k]);
        float e[9], sum = 0.f;
#pragma unroll
        for (int k = 0; k < 9; ++k) { e[k] = expf(sv[k] - mx); sum += e[k]; }
        const float rs = 1.f / sum;
#pragma unroll
        for (int k = 0; k < 9; ++k) ws9[k][w] = mk[k] * e[k] * rs;
    }
    __syncthreads();
    // ---- aggregation: lane = channel pair (u32 reads/writes), 16 px per thread
    const int cpair = (t & 127) * 2;
    const int pxg = t >> 7;
    u16* orow = xbo + (((size_t)(b * 4096 + h * 64)) << 9) + 256 + cpair;
#pragma unroll 4
    for (int pi = 0; pi < 16; ++pi) {
        const int px = pxg * 16 + pi;
        const int pL = px > 0 ? px - 1 : 0, pR = px < 63 ? px + 1 : 63;
        const int pxs[3] = {pL, px, pR};
        float m9[9];
#pragma unroll
        for (int k = 0; k < 9; ++k) m9[k] = ws9[k][px];
        float a0 = 0.f, a1 = 0.f;
#pragma unroll
        for (int r = 0; r < 3; ++r)
#pragma unroll
            for (int j = 0; j < 3; ++j) {
                const u32 vv = *(const u32*)(st + r * 16384 + pxs[j] * 256 + cpair);
                a0 = fmaf(bf2f((u16)(vv & 0xffffu)), m9[r * 3 + j], a0);
                a1 = fmaf(bf2f((u16)(vv >> 16)),     m9[r * 3 + j], a1);
            }
        *(u32*)(orow + ((size_t)px << 9)) = (u32)f2bf(a0) | ((u32)f2bf(a1) << 16);
    }
}

// ---------------- final: gate MLP (recomputed per block from pool) + residual add ----------------
// XCD map: b = id&7. W1/W2 (192 KB) are L2-resident; per-block recompute kills the
// serializing 8-block k_mlp dispatch.
__global__ __launch_bounds__(256) void k_final(
    const u16* __restrict__ xb, const u16* __restrict__ enh,
    const float* __restrict__ pool,
    const float* __restrict__ wg1, const float* __restrict__ bg1,
    const float* __restrict__ wg2, const float* __restrict__ bg2,
    float* __restrict__ out)
{
    __shared__ float pl[512];
    __shared__ float hpart[4][64];
    __shared__ float hb[64];
    __shared__ float sg[256];
    const int t = threadIdx.x;
    const int id = blockIdx.x;               // 512 = b(8) x 64 groups
    const int b = id & 7, rg = id >> 3;
    pl[t] = pool[b * 512 + t];
    pl[t + 256] = pool[b * 512 + 256 + t];
    __syncthreads();
    {
        const int o = t & 63, seg = t >> 6;
        float s = 0.f;
        const float* wr_ = wg1 + o * 512 + seg * 128;
        const float* pr_ = pl + seg * 128;
#pragma unroll 4
        for (int j = 0; j < 128; ++j) s = fmaf(wr_[j], pr_[j], s);
        hpart[seg][o] = s;
    }
    __syncthreads();
    if (t < 64)
        hb[t] = fmaxf(hpart[0][t] + hpart[1][t] + hpart[2][t] + hpart[3][t] + bg1[t], 0.f);
    __syncthreads();
    {
        float s2 = bg2[t];
        const float* w2 = wg2 + t * 64;
#pragma unroll 4
        for (int j = 0; j < 64; ++j) s2 = fmaf(w2[j], hb[j], s2);
        sg[t] = 1.f / (1.f + expf(-s2));
    }
    __syncthreads();
    const int w = t & 63, cs = t >> 6;
    const int p = rg * 64 + w;
    const u16* xrow = xb + (((size_t)(b * 4096 + p)) << 9) + cs * 64;
#pragma unroll 2
    for (int cc = 0; cc < 8; ++cc) {
        short8 xv = *(const short8*)(xrow + cc * 8);
#pragma unroll
        for (int u = 0; u < 8; ++u) {
            const int c = cs * 64 + cc * 8 + u;
            const float gt = sg[c];
            const size_t off = (((size_t)(b * 256 + c)) << 12) + p;
            out[off] = fmaf(gt, bf2f(enh[off]), bf2f((u16)xv[u]));
        }
    }
}

extern "C" void kernel_launch(void* const* d_in, const int* in_sizes, int n_in,
                              void* d_out, int out_size, void* d_ws, size_t ws_size,
                              hipStream_t stream)
{
    const float* x       = (const float*)d_in[0];
    const float* w_embed = (const float*)d_in[1];
    const float* b_embed = (const float*)d_in[2];
    const float* g1      = (const float*)d_in[3];
    const float* be1     = (const float*)d_in[4];
    const float* m1      = (const float*)d_in[5];
    const float* v1      = (const float*)d_in[6];
    const float* w_enh   = (const float*)d_in[7];
    const float* b_enh   = (const float*)d_in[8];
    const float* g2      = (const float*)d_in[9];
    const float* be2     = (const float*)d_in[10];
    const float* m2      = (const float*)d_in[11];
    const float* v2      = (const float*)d_in[12];
    const float* w_g1    = (const float*)d_in[13];
    const float* b_g1    = (const float*)d_in[14];
    const float* w_g2    = (const float*)d_in[15];
    const float* b_g2    = (const float*)d_in[16];
    float* ws  = (float*)d_ws;
    float* out = (float*)d_out;

    u16*   xb   = (u16*)(ws + OFS_XB);
    u16*   w1b  = (u16*)(ws + OFS_W1B);
    u16*   w2b  = (u16*)(ws + OFS_W2B);
    float* b1f  = ws + OFS_B1;
    float* b2f  = ws + OFS_B2;
    float* pool = ws + OFS_POOL;
    u16*   enh  = (u16*)(ws + OFS_ENH);
    u16*   fe   = (u16*)d_out;   // fe (bf16) lives in d_out; dead before k_final writes

    k_cvt<<<dim3(2819), dim3(256), 0, stream>>>(
        x, xb, pool,
        w_embed, b_embed, g1, be1, m1, v1,
        w_enh, b_enh, g2, be2, m2, v2, w1b, w2b, b1f, b2f);
    k_gemm<256, true, false><<<dim3(512), dim3(256), 0, stream>>>(xb, w1b, b1f, (void*)fe, nullptr);
    k_simagg<<<dim3(512), dim3(512), 0, stream>>>(fe, xb, xb);
    k_gemm<512, true, true><<<dim3(512), dim3(256), 0, stream>>>(xb, w2b, b2f, (void*)enh, pool);
    k_final<<<dim3(512), dim3(256), 0, stream>>>(xb, enh, pool, w_g1, b_g1, w_g2, b_g2, out);
}